// Round 2
// baseline (115.330 us; speedup 1.0000x reference)
//
#include <hip/hip_runtime.h>
#include <hip/hip_cooperative_groups.h>

namespace cg = cooperative_groups;

#define BBATCH 4
#define NN 1024
#define EE 32

typedef short v8s __attribute__((ext_vector_type(8)));
typedef float v4f __attribute__((ext_vector_type(4)));

__device__ __forceinline__ unsigned short f32_to_bf16(float v) {
    unsigned u = __builtin_bit_cast(unsigned, v);
    u += 0x7fffu + ((u >> 16) & 1u);      // round-to-nearest-even
    return (unsigned short)(u >> 16);
}

// ---------------------------------------------------------------------------
// Prep work item g in [0, 32768): fold coords into emb, bf16-convert (RNE),
// fp32 row norms from exact fp32 values.  8 lanes per row.
// ---------------------------------------------------------------------------
__device__ __forceinline__ void prep_work(int g,
    const float* __restrict__ emb, const float* __restrict__ coords,
    unsigned short* __restrict__ ybf, float* __restrict__ nrm)
{
    const int r  = g >> 3, qq = g & 7;               // row in [0,4096), quad
    float4 v = ((const float4*)emb)[g];
    if (qq == 0) { v.x += coords[r * 2 + 0]; v.y += coords[r * 2 + 1]; }
    ushort4 h;
    h.x = f32_to_bf16(v.x); h.y = f32_to_bf16(v.y);
    h.z = f32_to_bf16(v.z); h.w = f32_to_bf16(v.w);
    ((ushort4*)ybf)[g] = h;                          // linear [4096][32] bf16
    float p = v.x * v.x + v.y * v.y + v.z * v.z + v.w * v.w;
    #pragma unroll
    for (int off = 1; off < 8; off <<= 1) p += __shfl_xor(p, off, 64);
    if (qq == 0) nrm[r] = p;                         // fp32 norm of exact y
}

// ---------------------------------------------------------------------------
// Compute phase: one block = 16-row strip x all 1024 j of one batch.
// A/B fragments straight from global bf16 Y (L2-resident).  Verified body
// from round 1 (absmax 0.0).
// ---------------------------------------------------------------------------
__device__ __forceinline__ void compute_block(int bid, int tid,
    const unsigned short* __restrict__ ybf, const float* __restrict__ nrm,
    const int* __restrict__ mask, float* __restrict__ out,
    float (*sums_w)[16], float* total_s, float* wred)
{
    const int is = bid & 63;
    const int b  = bid >> 6;
    const int wave = tid >> 6, lane = tid & 63;
    const int m = lane & 15, q = lane >> 4;

    const unsigned short* Y  = ybf + (size_t)b * NN * EE;
    const float*          NR = nrm + b * NN;
    const int i0   = is * 16;
    const int irow = i0 + q * 4;          // this lane's 4 output rows

    const v8s af = *(const v8s*)(Y + (i0 + m) * EE + q * 8);
    float ni[4];
    #pragma unroll
    for (int r = 0; r < 4; ++r) ni[r] = NR[irow + r];

    const int jbase = wave * 64;          // 16 waves cover j = 0..1023
    float    ex[4][4];                    // exp(-sim) masked / exp(sim) neg
    float    s[4] = {0.f, 0.f, 0.f, 0.f};
    unsigned mbits = 0u;

    #pragma unroll
    for (int t = 0; t < 4; ++t) {
        const int j0 = jbase + t * 16;
        const v8s bfv = *(const v8s*)(Y + (j0 + m) * EE + q * 8);
        const float njv = NR[j0 + m];     // column j = j0+m
        int mk[4];
        #pragma unroll
        for (int r = 0; r < 4; ++r)
            mk[r] = mask[((size_t)(b * NN + irow + r) << 10) + j0 + m];
        v4f d = __builtin_amdgcn_mfma_f32_16x16x32_bf16(af, bfv, (v4f){0,0,0,0}, 0, 0, 0);
        #pragma unroll
        for (int r = 0; r < 4; ++r) {     // D row = q*4+r, col = m
            float nn   = ni[r] + njv;
            float ssq  = fmaxf(fmaf(-2.f, d[r], nn), 0.f);
            float dist = __builtin_amdgcn_sqrtf(ssq);
            float sm   = __builtin_amdgcn_rcpf(1.f + __expf(dist - 5.f));
            const float e = __expf(mk[r] != 0 ? -sm : sm);
            ex[t][r] = e;
            bool negm = (mk[r] != 0) || (irow + r == j0 + m);
            s[r] += negm ? 0.f : e;
            if (mk[r] != 0) mbits |= 1u << (t * 4 + r);
        }
    }

    // per-row totals: 16-lane reduce (over m) -> LDS[wave][row] -> sum 16 waves
    #pragma unroll
    for (int r = 0; r < 4; ++r) {
        float v = s[r];
        #pragma unroll
        for (int off = 8; off > 0; off >>= 1) v += __shfl_down(v, off, 16);
        if (m == 0) sums_w[wave][q * 4 + r] = v;
    }
    __syncthreads();
    if (tid < 16) {
        float tot = 0.f;
        #pragma unroll
        for (int w = 0; w < 16; ++w) tot += sums_w[w][tid];
        total_s[tid] = tot;
    }
    __syncthreads();

    // phase 2: masked pairs, term = log1p(total_i * exp(-sim)); total=0 -> 0
    float tot[4];
    #pragma unroll
    for (int r = 0; r < 4; ++r) tot[r] = total_s[q * 4 + r];
    float acc = 0.f;
    #pragma unroll
    for (int t = 0; t < 4; ++t)
        #pragma unroll
        for (int r = 0; r < 4; ++r) {
            float lg = __logf(fmaf(tot[r], ex[t][r], 1.f));
            acc += ((mbits >> (t * 4 + r)) & 1u) ? lg : 0.f;
        }

    #pragma unroll
    for (int off = 32; off > 0; off >>= 1) acc += __shfl_down(acc, off, 64);
    if (lane == 0) wred[wave] = acc;
    __syncthreads();
    if (tid == 0) {
        float a = 0.f;
        #pragma unroll
        for (int w = 0; w < 16; ++w) a += wred[w];
        atomicAdd(out, a);                // 256 atomics total
    }
}

// ---------------------------------------------------------------------------
// Single-dispatch cooperative kernel: prep + out-zero, grid sync, compute.
// 256 blocks x 1024 threads = 1 block/CU (16 waves), co-resident.
// ---------------------------------------------------------------------------
__global__ __launch_bounds__(1024) void fused_coop(
    const float* __restrict__ emb, const float* __restrict__ coords,
    const int* __restrict__ mask, float* __restrict__ out,
    unsigned short* __restrict__ ybf, float* __restrict__ nrm)
{
    __shared__ float sums_w[16][16];
    __shared__ float total_s[16];
    __shared__ float wred[16];

    const int g = blockIdx.x * 1024 + threadIdx.x;
    if (g < BBATCH * NN * EE / 4) prep_work(g, emb, coords, ybf, nrm);
    if (g == 0) out[0] = 0.f;             // replaces hipMemsetAsync dispatch
    cg::this_grid().sync();               // device-scope visibility incl. cross-XCD
    compute_block(blockIdx.x, threadIdx.x, ybf, nrm, mask, out,
                  sums_w, total_s, wred);
}

// ---------------------------------------------------------------------------
// Fallback path (if cooperative launch is rejected): 2 dispatches, no memset.
// ---------------------------------------------------------------------------
__global__ __launch_bounds__(1024) void prep_z_kernel(
    const float* __restrict__ emb, const float* __restrict__ coords,
    unsigned short* __restrict__ ybf, float* __restrict__ nrm,
    float* __restrict__ out)
{
    const int g = blockIdx.x * 1024 + threadIdx.x;   // grid 32 x 1024 = 32768
    prep_work(g, emb, coords, ybf, nrm);
    if (g == 0) out[0] = 0.f;
}

__global__ __launch_bounds__(1024) void fused_kernel(
    const unsigned short* __restrict__ ybf, const float* __restrict__ nrm,
    const int* __restrict__ mask, float* __restrict__ out)
{
    __shared__ float sums_w[16][16];
    __shared__ float total_s[16];
    __shared__ float wred[16];
    compute_block(blockIdx.x, threadIdx.x, ybf, nrm, mask, out,
                  sums_w, total_s, wred);
}

extern "C" void kernel_launch(void* const* d_in, const int* in_sizes, int n_in,
                              void* d_out, int out_size, void* d_ws, size_t ws_size,
                              hipStream_t stream) {
    const float* emb    = (const float*)d_in[0];
    const float* coords = (const float*)d_in[1];
    const int*   mask   = (const int*)d_in[2];
    float*       out    = (float*)d_out;

    unsigned short* ybf = (unsigned short*)d_ws;                        // 256 KB
    float*          nrv = (float*)((char*)d_ws + BBATCH * NN * EE * 2); // +16 KB

    void* kargs[] = {(void*)&emb, (void*)&coords, (void*)&mask,
                     (void*)&out, (void*)&ybf, (void*)&nrv};
    hipError_t e = hipLaunchCooperativeKernel(
        reinterpret_cast<void*>(fused_coop),
        dim3(BBATCH * (NN / 16)), dim3(1024), kargs, 0, stream);
    if (e != hipSuccess) {
        (void)hipGetLastError();          // clear sticky error, use fallback
        prep_z_kernel<<<32, 1024, 0, stream>>>(emb, coords, ybf, nrv, out);
        fused_kernel<<<BBATCH * (NN / 16), 1024, 0, stream>>>(ybf, nrv, mask, out);
    }
}

// Round 3
// 80.205 us; speedup vs baseline: 1.4379x; 1.4379x over previous
//
#include <hip/hip_runtime.h>

#define BBATCH 4
#define NN 1024
#define EE 32

typedef short v8s __attribute__((ext_vector_type(8)));
typedef float v4f __attribute__((ext_vector_type(4)));

__device__ __forceinline__ unsigned short f32_to_bf16(float v) {
    unsigned u = __builtin_bit_cast(unsigned, v);
    u += 0x7fffu + ((u >> 16) & 1u);      // round-to-nearest-even
    return (unsigned short)(u >> 16);
}

// Load one MFMA fragment row (8 of 32 cols) straight from fp32 emb, fold
// coords into cols 0/1, compute the full fp32 row norm via a 4-lane
// cross-quad reduce (lanes m, m+16, m+32, m+48 hold the 4 quads of a row),
// and pack to bf16.  Replaces the prep kernel + d_ws round-trip entirely.
__device__ __forceinline__ v8s load_frag(const float* __restrict__ Eb,
                                         const float* __restrict__ Cb,
                                         int row, int q, float& nrm_out)
{
    const float4* p = (const float4*)(Eb + row * EE + q * 8);
    float4 v0 = p[0], v1 = p[1];
    if (q == 0) { v0.x += Cb[row * 2 + 0]; v0.y += Cb[row * 2 + 1]; }
    float s = v0.x*v0.x + v0.y*v0.y + v0.z*v0.z + v0.w*v0.w
            + v1.x*v1.x + v1.y*v1.y + v1.z*v1.z + v1.w*v1.w;
    s += __shfl_xor(s, 16, 64);           // combine the 4 q-lanes of this row
    s += __shfl_xor(s, 32, 64);
    nrm_out = s;                          // fp32 norm of exact y[row]
    v8s f;
    f[0] = (short)f32_to_bf16(v0.x); f[1] = (short)f32_to_bf16(v0.y);
    f[2] = (short)f32_to_bf16(v0.z); f[3] = (short)f32_to_bf16(v0.w);
    f[4] = (short)f32_to_bf16(v1.x); f[5] = (short)f32_to_bf16(v1.y);
    f[6] = (short)f32_to_bf16(v1.z); f[7] = (short)f32_to_bf16(v1.w);
    return f;
}

// One block = 16-row strip x all 1024 j of one batch.  Fully standalone:
// fragments converted in-register from fp32 emb (L2-resident, ~10 KB/wave);
// no prep kernel, no d_ws, no staging LDS.  MFMA 16x16x32 bf16, D layout
// col=lane&15, row=(lane>>4)*4+reg (m89).
__global__ __launch_bounds__(1024) void fused_kernel(
    const float* __restrict__ emb, const float* __restrict__ coords,
    const int* __restrict__ mask, float* __restrict__ out)
{
    const int bid = blockIdx.x;           // b(2) | istrip(6)
    const int is = bid & 63;
    const int b  = bid >> 6;
    const int tid  = threadIdx.x;
    const int wave = tid >> 6, lane = tid & 63;
    const int m = lane & 15, q = lane >> 4;

    __shared__ float sums_w[16][16];
    __shared__ float total_s[16];
    __shared__ float wred[16];

    const float* Eb = emb    + (size_t)b * NN * EE;
    const float* Cb = coords + (size_t)b * NN * 2;
    const int i0   = is * 16;
    const int irow = i0 + q * 4;          // this lane's 4 output rows

    // A fragment: row i0+m, cols q*8..q*8+7
    float na;                             // norm of row i0+m (all q-lanes)
    const v8s af = load_frag(Eb, Cb, i0 + m, q, na);
    float ni[4];
    #pragma unroll
    for (int r = 0; r < 4; ++r)           // norm of row i0+q*4+r: fetch from
        ni[r] = __shfl(na, q * 4 + r, 16);// lane (q, m'=q*4+r) in this segment

    const int jbase = wave * 64;          // 16 waves cover j = 0..1023
    float    ex[4][4];                    // exp(-sim) masked / exp(sim) neg
    float    s[4] = {0.f, 0.f, 0.f, 0.f};
    unsigned mbits = 0u;

    #pragma unroll
    for (int t = 0; t < 4; ++t) {
        const int j0 = jbase + t * 16;
        float njv;                        // norm of column j = j0+m
        const v8s bfv = load_frag(Eb, Cb, j0 + m, q, njv);
        int mk[4];
        #pragma unroll
        for (int r = 0; r < 4; ++r)
            mk[r] = mask[((size_t)(b * NN + irow + r) << 10) + j0 + m];
        v4f d = __builtin_amdgcn_mfma_f32_16x16x32_bf16(af, bfv, (v4f){0,0,0,0}, 0, 0, 0);
        #pragma unroll
        for (int r = 0; r < 4; ++r) {     // D row = q*4+r, col = m
            float nn   = ni[r] + njv;
            float ssq  = fmaxf(fmaf(-2.f, d[r], nn), 0.f);
            float dist = __builtin_amdgcn_sqrtf(ssq);
            float sm   = __builtin_amdgcn_rcpf(1.f + __expf(dist - 5.f));
            const float e = __expf(mk[r] != 0 ? -sm : sm);
            ex[t][r] = e;
            bool negm = (mk[r] != 0) || (irow + r == j0 + m);
            s[r] += negm ? 0.f : e;
            if (mk[r] != 0) mbits |= 1u << (t * 4 + r);
        }
    }

    // per-row totals: 16-lane reduce (over m) -> LDS[wave][row] -> sum 16 waves
    #pragma unroll
    for (int r = 0; r < 4; ++r) {
        float v = s[r];
        #pragma unroll
        for (int off = 8; off > 0; off >>= 1) v += __shfl_down(v, off, 16);
        if (m == 0) sums_w[wave][q * 4 + r] = v;
    }
    __syncthreads();
    if (tid < 16) {
        float tot = 0.f;
        #pragma unroll
        for (int w = 0; w < 16; ++w) tot += sums_w[w][tid];
        total_s[tid] = tot;
    }
    __syncthreads();

    // phase 2: masked pairs, term = log1p(total_i * exp(-sim)); total=0 -> 0
    float tot[4];
    #pragma unroll
    for (int r = 0; r < 4; ++r) tot[r] = total_s[q * 4 + r];
    float acc = 0.f;
    #pragma unroll
    for (int t = 0; t < 4; ++t)
        #pragma unroll
        for (int r = 0; r < 4; ++r) {
            float lg = __logf(fmaf(tot[r], ex[t][r], 1.f));
            acc += ((mbits >> (t * 4 + r)) & 1u) ? lg : 0.f;
        }

    #pragma unroll
    for (int off = 32; off > 0; off >>= 1) acc += __shfl_down(acc, off, 64);
    if (lane == 0) wred[wave] = acc;
    __syncthreads();
    if (tid == 0) {
        float a = 0.f;
        #pragma unroll
        for (int w = 0; w < 16; ++w) a += wred[w];
        atomicAdd(out, a);                // 256 atomics total
    }
}

extern "C" void kernel_launch(void* const* d_in, const int* in_sizes, int n_in,
                              void* d_out, int out_size, void* d_ws, size_t ws_size,
                              hipStream_t stream) {
    const float* emb    = (const float*)d_in[0];
    const float* coords = (const float*)d_in[1];
    const int*   mask   = (const int*)d_in[2];
    float*       out    = (float*)d_out;

    hipMemsetAsync(out, 0, sizeof(float), stream);   // d_out is 0xAA-poisoned
    fused_kernel<<<BBATCH * (NN / 16), 1024, 0, stream>>>(emb, coords, mask, out);
}